// Round 1
// baseline (74.699 us; speedup 1.0000x reference)
//
#include <hip/hip_runtime.h>

#define NPAIRS 1048576
#define MAX_STEPS 16

__global__ __launch_bounds__(256) void flow_cost_kernel(
    const float4* __restrict__ x1,
    const float4* __restrict__ x2,
    const float*  __restrict__ params,   // [3][2] row-major: p00 p01 p10 p11 p20 p21
    float2*       __restrict__ out,
    int n2)                              // number of pair-pairs (P/2)
{
    int i = blockIdx.x * blockDim.x + threadIdx.x;
    if (i >= n2) return;

    // broadcast params (L1/L2 cached; uniform address)
    const float p00 = params[0], p01 = params[1];
    const float p10 = params[2], p11 = params[3];
    const float p20 = params[4], p21 = params[5];

    const float4 a = x1[i];   // two pairs: (x1[2i], x1[2i+1])
    const float4 b = x2[i];

    float res[2];
#pragma unroll
    for (int q = 0; q < 2; ++q) {
        const float ax = q ? a.z : a.x, ay = q ? a.w : a.y;
        const float bx = q ? b.z : b.x, by = q ? b.w : b.y;
        const float dx = bx - ax, dy = by - ay;
        const float euc = sqrtf(fmaf(dx, dx, dy * dy));
        const float inv = 1.0f / euc;
        const float ux = dx * inv, uy = dy * inv;

        // c_k = params[k] . d, with binomial coeff 3 folded into c1,c2
        const float c0 =        fmaf(p00, dx, p01 * dy);
        const float c1 = 3.0f * fmaf(p10, dx, p11 * dy);
        const float c2 = 3.0f * fmaf(p20, dx, p21 * dy);

        // n_valid = floor(euc/STEP)+1 — true division to match jnp exactly
        int n_valid = (int)floorf(euc / 0.1f) + 1;
        if (n_valid > MAX_STEPS) n_valid = MAX_STEPS;

        float sum = 0.0f;
#pragma unroll
        for (int t = 0; t < MAX_STEPS; ++t) {
            const float s = 0.1f * (float)t;
            const float x = fmaf(s, ux, ax);
            const float y = fmaf(s, uy, ay);
            const float xx = x * x;
            const float xy = x * y;
            const float lin = fmaf(c0, x, c1 * y);          // c0*x + c1*y
            const float dot = fmaf(xx, lin, c2 * xy * y);   // x^3 c0 + x^2 y c1 + x y^2 c2
            const float e = __expf(-dot);                    // 0.08/exp(dot) term
            sum += (t < n_valid) ? e : 0.0f;                 // select, no divergence
        }
        res[q] = fmaf(0.08f, sum, 0.02f * (float)n_valid);
    }

    out[i] = make_float2(res[0], res[1]);
}

extern "C" void kernel_launch(void* const* d_in, const int* in_sizes, int n_in,
                              void* d_out, int out_size, void* d_ws, size_t ws_size,
                              hipStream_t stream) {
    const float4* x1 = (const float4*)d_in[0];
    const float4* x2 = (const float4*)d_in[1];
    const float*  pp = (const float*)d_in[2];
    float2* out = (float2*)d_out;

    const int n2 = NPAIRS / 2;               // 524288 threads, one per 2 pairs
    const int block = 256;
    const int grid = (n2 + block - 1) / block;  // 2048 blocks
    flow_cost_kernel<<<grid, block, 0, stream>>>(x1, x2, pp, out, n2);
}

// Round 2
// 69.295 us; speedup vs baseline: 1.0780x; 1.0780x over previous
//
#include <hip/hip_runtime.h>

#define NPAIRS 1048576
#define MAX_STEPS 16

#if __has_builtin(__builtin_amdgcn_exp2f)
#define EXP2F(x) __builtin_amdgcn_exp2f(x)
#else
#define EXP2F(x) exp2f(x)
#endif

__global__ __launch_bounds__(256) void flow_cost_kernel(
    const float4* __restrict__ x1,
    const float4* __restrict__ x2,
    const float*  __restrict__ params,   // [3][2]: p00 p01 p10 p11 p20 p21
    float4*       __restrict__ out,
    int n4)                              // P/4 threads, 4 pairs each
{
    const int i = blockIdx.x * blockDim.x + threadIdx.x;
    if (i >= n4) return;

    const float p00 = params[0], p01 = params[1];
    const float p10 = params[2], p11 = params[3];
    const float p20 = params[4], p21 = params[5];

    const float4 a0 = x1[2 * i], a1 = x1[2 * i + 1];
    const float4 b0 = x2[2 * i], b1 = x2[2 * i + 1];

    const float ax[4] = {a0.x, a0.z, a1.x, a1.z};
    const float ay[4] = {a0.y, a0.w, a1.y, a1.w};
    const float bx[4] = {b0.x, b0.z, b1.x, b1.z};
    const float by[4] = {b0.y, b0.w, b1.y, b1.w};

    const float NL2E = -1.44269504088896340736f;   // -log2(e)

    float A[4], B[4], C[4], D[4], sum[4];
    int nv[4];

#pragma unroll
    for (int q = 0; q < 4; ++q) {
        const float dx = bx[q] - ax[q], dy = by[q] - ay[q];
        const float s2  = fmaf(dx, dx, dy * dy);
        const float euc = sqrtf(s2);
        // n_valid: bit-identical to the round-1 passing version (floor boundary!)
        int n = (int)floorf(euc / 0.1f) + 1;
        if (n > MAX_STEPS) n = MAX_STEPS;
        nv[q] = n;

        const float inv = 1.0f / euc;
        const float u = 0.1f * dx * inv;   // per-step advance in x
        const float v = 0.1f * dy * inv;   // per-step advance in y

        // c_k = params[k].d, binomial 3 and -log2(e) folded in
        const float c0 = NL2E *        fmaf(p00, dx, p01 * dy);
        const float c1 = NL2E * 3.0f * fmaf(p10, dx, p11 * dy);
        const float c2 = NL2E * 3.0f * fmaf(p20, dx, p21 * dy);

        const float a = ax[q], b = ay[q];
        const float u2 = u * u, v2 = v * v, uv = u * v;
        const float a2 = a * a, b2 = b * b, ab = a * b;

        // dot'(t) = A t^3 + B t^2 + C t + D   (pre-scaled by -log2 e)
        A[q] = fmaf(c0, u2 * u,
               fmaf(c1, u2 * v, c2 * uv * v));
        B[q] = fmaf(3.0f * c0, a * u2,
               fmaf(c1, fmaf(2.0f * a, uv, b * u2),
                    c2 * fmaf(2.0f * b, uv, a * v2)));
        C[q] = fmaf(3.0f * c0, a2 * u,
               fmaf(c1, fmaf(2.0f * u, ab, a2 * v),
                    c2 * fmaf(2.0f * v, ab, b2 * u)));
        D[q] = fmaf(c0, a2 * a,
               fmaf(c1, a2 * b, c2 * ab * b));
        sum[q] = 0.0f;
    }

#pragma unroll
    for (int t = 0; t < MAX_STEPS; ++t) {
        const float tf = (float)t;
#pragma unroll
        for (int q = 0; q < 4; ++q) {
            const float w = fmaf(fmaf(fmaf(A[q], tf, B[q]), tf, C[q]), tf, D[q]);
            const float e = EXP2F(w);                 // raw v_exp_f32
            sum[q] += (t < nv[q]) ? e : 0.0f;         // select, no divergence
        }
    }

    float4 r;
    r.x = fmaf(0.08f, sum[0], 0.02f * (float)nv[0]);
    r.y = fmaf(0.08f, sum[1], 0.02f * (float)nv[1]);
    r.z = fmaf(0.08f, sum[2], 0.02f * (float)nv[2]);
    r.w = fmaf(0.08f, sum[3], 0.02f * (float)nv[3]);
    out[i] = r;
}

extern "C" void kernel_launch(void* const* d_in, const int* in_sizes, int n_in,
                              void* d_out, int out_size, void* d_ws, size_t ws_size,
                              hipStream_t stream) {
    const float4* x1 = (const float4*)d_in[0];
    const float4* x2 = (const float4*)d_in[1];
    const float*  pp = (const float*)d_in[2];
    float4* out = (float4*)d_out;

    const int n4 = NPAIRS / 4;                   // 262144 threads, 4 pairs each
    const int block = 256;
    const int grid = (n4 + block - 1) / block;   // 1024 blocks
    flow_cost_kernel<<<grid, block, 0, stream>>>(x1, x2, pp, out, n4);
}